// Round 14
// baseline (292.033 us; speedup 1.0000x reference)
//
#include <hip/hip_runtime.h>
#include <math.h>

// ---------------------------------------------------------------------------
// HybridBERT4RecGNN forward on MI355X (gfx950), round 25.
//
// R24: 291.4us; transformer 78.2us at 42% occupancy -- chain-bound (2x
// occupancy bought only -6%), occupancy lever exhausted.
// R25:
//  (a) build partitioning P=8 -> P=4: reads 88MB -> 48MB (dst 4 passes,
//      src/ew lines ~4x), writes 13 -> ~26MB (partition spans 2 XCDs under
//      round-robin) => net -27MB => ~-10us.
//  (b) s_setprio(1)/(0) around transformer MFMA clusters (T5): measured
//      +4-7% for independent co-resident blocks at different phases (our
//      regime: 4 blocks/CU, barriers only within a block). Hint-only.
// Everything else byte-identical to R24 (passed).
// ---------------------------------------------------------------------------

typedef __attribute__((ext_vector_type(8))) short bf16x8;
typedef __attribute__((ext_vector_type(4))) float f32x4;

#define SD   64
#define SS   50
#define NBLK 2
#define PH   72    // LDS pitch in halves (144 B, 16B-aligned rows, 2-way banks max)
#define OVCAP 8192

__device__ __forceinline__ short f2b(float f) {  // fp32 -> bf16 RNE (HW cvt)
  union { __bf16 h; short s; } u;
  u.h = (__bf16)f;
  return u.s;
}
__device__ __forceinline__ float b2f(short s) {
  union { unsigned u; float f; } v;
  v.u = ((unsigned)(unsigned short)s) << 16;
  return v.f;
}
__device__ __forceinline__ unsigned packb(float a, float b) {
  union { __bf16 h; unsigned short s; } ua, ub;
  ua.h = (__bf16)a; ub.h = (__bf16)b;
  return (unsigned)ua.s | ((unsigned)ub.s << 16);
}
__device__ __forceinline__ float2 wred_sum2(float a, float b) {
#pragma unroll
  for (int o = 32; o > 0; o >>= 1) {
    a += __shfl_xor(a, o, 64);
    b += __shfl_xor(b, o, 64);
  }
  return make_float2(a, b);
}
// gelu(x) = 0.5x(1+tanh(u)) = x * sigmoid(2u);  sigmoid via v_rcp_f32.
__device__ __forceinline__ float gelu_fast(float x) {
  float u = 0.7978845608028654f * x * (1.0f + 0.044715f * x * x);
  float e = __expf(-2.f * u);
  return x * __builtin_amdgcn_rcpf(1.0f + e);
}

__device__ __forceinline__ bf16x8 ldB(const short* __restrict__ Wb, int tile, int lane) {
  return *(const bf16x8*)(Wb + ((size_t)tile * 64 + lane) * 8);
}

// [own 16 rows x K=64] @ [64x64] -> D own rows. A from LDS bf16 pitch PH.
// setprio(1) keeps the matrix pipe fed while other blocks issue memory ops.
__device__ __forceinline__ void mm64(const short* A, const short* __restrict__ Wb,
                                     int arow, int quad, int lane, f32x4 o4[4]) {
  bf16x8 a0 = *(const bf16x8*)(A + arow * PH + quad * 8);
  bf16x8 a1 = *(const bf16x8*)(A + arow * PH + 32 + quad * 8);
  __builtin_amdgcn_s_setprio(1);
#pragma unroll
  for (int nt = 0; nt < 4; ++nt) {
    f32x4 acc = {0.f, 0.f, 0.f, 0.f};
    acc = __builtin_amdgcn_mfma_f32_16x16x32_bf16(a0, ldB(Wb, 0 * 4 + nt, lane), acc, 0, 0, 0);
    acc = __builtin_amdgcn_mfma_f32_16x16x32_bf16(a1, ldB(Wb, 1 * 4 + nt, lane), acc, 0, 0, 0);
    o4[nt] = acc;
  }
  __builtin_amdgcn_s_setprio(0);
}

// LN over 64 cols of D-layout values + residual from xh + optional bias.
__device__ __forceinline__ void ln_epilogue(f32x4 o4[4], short* xh,
                                            const float* __restrict__ g,
                                            const float* __restrict__ bta,
                                            const float* __restrict__ extrab,
                                            int mt, int quad, int c0) {
  float vals[4][4];
  float s1[4] = {0.f, 0.f, 0.f, 0.f}, s2[4] = {0.f, 0.f, 0.f, 0.f};
#pragma unroll
  for (int nt = 0; nt < 4; ++nt) {
    int c = nt * 16 + c0;
    float eb = extrab ? extrab[c] : 0.f;
#pragma unroll
    for (int r = 0; r < 4; ++r) {
      int row = mt * 16 + quad * 4 + r;
      float v = o4[nt][r] + b2f(xh[row * PH + c]) + eb;
      vals[nt][r] = v;
      s1[r] += v;
      s2[r] += v * v;
    }
  }
#pragma unroll
  for (int o = 1; o < 16; o <<= 1) {
#pragma unroll
    for (int r = 0; r < 4; ++r) {
      s1[r] += __shfl_xor(s1[r], o, 64);
      s2[r] += __shfl_xor(s2[r], o, 64);
    }
  }
  float mv[4], rv[4];
#pragma unroll
  for (int r = 0; r < 4; ++r) {
    float m = s1[r] * (1.f / 64);
    float var = fmaxf(s2[r] * (1.f / 64) - m * m, 0.f);
    mv[r] = m;
    rv[r] = rsqrtf(var + 1e-5f);
  }
#pragma unroll
  for (int nt = 0; nt < 4; ++nt) {
    int c = nt * 16 + c0;
    float gv = g[c], bv = bta[c];
#pragma unroll
    for (int r = 0; r < 4; ++r) {
      int row = mt * 16 + quad * 4 + r;
      xh[row * PH + c] = f2b((vals[nt][r] - mv[r]) * rv[r] * gv + bv);
    }
  }
}

// ---------------------------------------------------------------------------
// Weight prep body
// ---------------------------------------------------------------------------
__device__ __forceinline__ void prep_body(int tid,
    const float* __restrict__ pw, const float* __restrict__ wq,
    const float* __restrict__ wk, const float* __restrict__ wv,
    const float* __restrict__ wo, const float* __restrict__ w1,
    const float* __restrict__ w2,
    short* __restrict__ pwB, short* __restrict__ wqB,
    short* __restrict__ wkB, short* __restrict__ wvB,
    short* __restrict__ woB, short* __restrict__ w1B,
    short* __restrict__ w2B) {
  int lane = tid & 63;
  int tile = tid >> 6;
  const float* W; short* out; int K, N, base;
  if (tile < 8)        { W = pw; out = pwB; K = 64;  N = 64;  base = 0; }
  else if (tile < 24)  { W = wq; out = wqB; K = 64;  N = 64;  base = 8; }
  else if (tile < 40)  { W = wk; out = wkB; K = 64;  N = 64;  base = 24; }
  else if (tile < 56)  { W = wv; out = wvB; K = 64;  N = 64;  base = 40; }
  else if (tile < 72)  { W = wo; out = woB; K = 64;  N = 64;  base = 56; }
  else if (tile < 136) { W = w1; out = w1B; K = 64;  N = 256; base = 72; }
  else if (tile < 200) { W = w2; out = w2B; K = 256; N = 64;  base = 136; }
  else return;
  int lt = tile - base;
  int KT = K / 32, NT = N / 16;
  int nt = lt % NT; lt /= NT;
  int kt = lt % KT; lt /= KT;
  int m = lt;
  const float* Wm = W + (size_t)m * K * N;
  int kbase = kt * 32 + ((lane >> 4) * 8);
  int n = nt * 16 + (lane & 15);
  short v[8];
#pragma unroll
  for (int j = 0; j < 8; ++j) v[j] = f2b(Wm[(size_t)(kbase + j) * N + n]);
  *(bf16x8*)(out + ((size_t)(tile - base) * 64 + lane) * 8) = *(bf16x8*)v;
}

// Tiny kernel: zero counters/flags/ovcnt (kernel-based; memset banned).
__global__ void zero_only(int* __restrict__ cntp, int cntn,
                          int* __restrict__ flagsw, int nfw,
                          int* __restrict__ ovcnt) {
  int tid = blockIdx.x * blockDim.x + threadIdx.x;
  int NT = gridDim.x * blockDim.x;
  for (int i = tid; i < cntn; i += NT) cntp[i] = 0;
  for (int i = tid; i < nfw; i += NT) flagsw[i] = 0;
  if (tid < 4) ovcnt[tid] = 0;
}

// ---------------------------------------------------------------------------
// Fused: weight prep + fp32->bf16 cvt + flags + slot-direct CSR build.
// P=4 dst partitions (bid&3): dst read 4x (16MB) + src/ew ~4x (32MB) vs
// P=8's ~88MB; each partition spans 2 XCDs (round-robin) -> ~2x write amp
// on 13MB. Net ~-27MB traffic.
// ---------------------------------------------------------------------------
__global__ void gnn_build(const int* __restrict__ src, const int* __restrict__ dst,
                          const float* __restrict__ ew, int* __restrict__ cntp,
                          int cs, int cap, int2* __restrict__ ep,
                          int4* __restrict__ ov, int* __restrict__ ovcnt,
                          const int* __restrict__ seq,
                          unsigned char* __restrict__ flags, int BS,
                          int E, int Nn,
                          const float* __restrict__ gnn, unsigned* __restrict__ gnnh,
                          int n32,
                          const float* __restrict__ pw, const float* __restrict__ wq,
                          const float* __restrict__ wk, const float* __restrict__ wv,
                          const float* __restrict__ wo, const float* __restrict__ w1,
                          const float* __restrict__ w2,
                          short* __restrict__ pwB, short* __restrict__ wqB,
                          short* __restrict__ wkB, short* __restrict__ wvB,
                          short* __restrict__ woB, short* __restrict__ w1B,
                          short* __restrict__ w2B) {
  int tid = blockIdx.x * 256 + threadIdx.x;
  int NT = gridDim.x * 256;
  prep_body(tid, pw, wq, wk, wv, wo, w1, w2, pwB, wqB, wkB, wvB, woB, w1B, w2B);
  for (int i = tid; i < n32; i += NT) {
    float2 f = ((const float2*)gnn)[i];
    gnnh[i] = packb(f.x, f.y);
  }
  for (int i = tid; i < BS; i += NT) flags[seq[i]] = 1;
  int p = blockIdx.x & 3;
  int sub = blockIdx.x >> 2;
  int nsub = gridDim.x >> 2;
  int lo = (int)(((long)p * Nn) >> 2);
  int hi = (int)(((long)(p + 1) * Nn) >> 2);
  for (int e = sub * 256 + threadIdx.x; e < E; e += nsub * 256) {
    int d = dst[e];
    if (d >= lo && d < hi) {
      int pos = atomicAdd(&cntp[d * cs], 1);
      if (pos < cap) {
        ep[(size_t)d * cap + pos] = make_int2(src[e], __float_as_int(ew[e]));
      } else {
        int oi = atomicAdd(ovcnt, 1);
        if (oi < OVCAP) ov[oi] = make_int4(d, src[e], __float_as_int(ew[e]), 0);
      }
    }
  }
}

// ---------------------------------------------------------------------------
// Gather: half-wave (32 lanes) per node, 4 slots x 8 dims. ep speculative
// (|| cnt); rows predicated by slot+4b<end. 2 dependent levels for deg<=16.
// ---------------------------------------------------------------------------
__device__ __forceinline__ void gather_accum(float a[8], uint4 p, float w) {
  a[0] += b2f((short)(p.x & 0xFFFF)) * w;
  a[1] += b2f((short)(p.x >> 16)) * w;
  a[2] += b2f((short)(p.y & 0xFFFF)) * w;
  a[3] += b2f((short)(p.y >> 16)) * w;
  a[4] += b2f((short)(p.z & 0xFFFF)) * w;
  a[5] += b2f((short)(p.z >> 16)) * w;
  a[6] += b2f((short)(p.w & 0xFFFF)) * w;
  a[7] += b2f((short)(p.w >> 16)) * w;
}
__device__ __forceinline__ void gather_accum_idx(float a[8],
    const unsigned* __restrict__ tab, int srcn, float w, int g) {
  uint4 p = *(const uint4*)(tab + (size_t)srcn * 32 + g * 4);
  gather_accum(a, p, w);
}

__device__ __forceinline__ void gather_core(float a[8], int n, int slot, int g,
    const unsigned* __restrict__ tab, const int* __restrict__ cntp, int cs, int cap,
    const int2* __restrict__ ep, const int4* __restrict__ ov,
    const int* __restrict__ ovcnt, int Nn) {
  int deg = cntp[n * cs];                       // level-1, concurrent with:
  int2 e[4];
#pragma unroll
  for (int b = 0; b < 4; ++b)                   // slots 0..15 < cap, in-bounds
    e[b] = ep[(size_t)n * cap + slot + 4 * b];
  int end = min(deg, cap);
  uint4 r[4] = {};
#pragma unroll
  for (int b = 0; b < 4; ++b) {                 // level-2: predicated rows
    if (slot + 4 * b < end) {
      int s = min(max(e[b].x, 0), Nn - 1);
      r[b] = *(const uint4*)(tab + (size_t)s * 32 + g * 4);
    }
  }
#pragma unroll
  for (int b = 0; b < 4; ++b)
    if (slot + 4 * b < end) gather_accum(a, r[b], __int_as_float(e[b].y));
  for (int i = slot + 16; i < end; i += 4) {    // tail: 16 < deg <= cap (2.7%)
    int2 ee = ep[(size_t)n * cap + i];
    gather_accum_idx(a, tab, min(max(ee.x, 0), Nn - 1), __int_as_float(ee.y), g);
  }
  if (deg > cap && slot == 0) {   // rare path: scan overflow list once
    int ovn = min(max(*ovcnt, 0), OVCAP);
    for (int i = 0; i < ovn; ++i) {
      int4 eo = ov[i];
      if (eo.x == n) gather_accum_idx(a, tab, min(max(eo.y, 0), Nn - 1),
                                      __int_as_float(eo.z), g);
    }
  }
}

__global__ void gnn_gather1(const unsigned* __restrict__ xinh,
                            const int* __restrict__ cntp, int cs, int cap,
                            const int2* __restrict__ ep, const int4* __restrict__ ov,
                            const int* __restrict__ ovcnt,
                            unsigned* __restrict__ xouth, int Nn) {
  int l32 = threadIdx.x & 31;
  int slot = l32 >> 3, g = l32 & 7;
  for (int n = blockIdx.x * 8 + (threadIdx.x >> 5); n < Nn; n += gridDim.x * 8) {
    float a[8] = {0.f, 0.f, 0.f, 0.f, 0.f, 0.f, 0.f, 0.f};
    gather_core(a, n, slot, g, xinh, cntp, cs, cap, ep, ov, ovcnt, Nn);
#pragma unroll
    for (int o = 8; o < 32; o <<= 1)
#pragma unroll
      for (int j = 0; j < 8; ++j) a[j] += __shfl_xor(a[j], o, 64);
    if (slot == 0) {
      uint4 o4;
      o4.x = packb(a[0], a[1]);
      o4.y = packb(a[2], a[3]);
      o4.z = packb(a[4], a[5]);
      o4.w = packb(a[6], a[7]);
      *(uint4*)(xouth + (size_t)n * 32 + g * 4) = o4;
    }
  }
}

__global__ void gnn_gather_avg(const unsigned* __restrict__ x1h,
                               const int* __restrict__ cntp, int cs, int cap,
                               const int2* __restrict__ ep, const int4* __restrict__ ov,
                               const int* __restrict__ ovcnt,
                               const float* __restrict__ gnn,
                               unsigned* __restrict__ avgh, int Nn,
                               const unsigned char* __restrict__ flags) {
  int l32 = threadIdx.x & 31;
  int slot = l32 >> 3, g = l32 & 7;
  for (int n = blockIdx.x * 8 + (threadIdx.x >> 5); n < Nn; n += gridDim.x * 8) {
    if (!flags[n]) continue;   // avgh[n] never read by transformer
    float a[8] = {0.f, 0.f, 0.f, 0.f, 0.f, 0.f, 0.f, 0.f};
    gather_core(a, n, slot, g, x1h, cntp, cs, cap, ep, ov, ovcnt, Nn);
#pragma unroll
    for (int o = 8; o < 32; o <<= 1)
#pragma unroll
      for (int j = 0; j < 8; ++j) a[j] += __shfl_xor(a[j], o, 64);
    if (slot == 0) {
      uint4 own = *(const uint4*)(x1h + (size_t)n * 32 + g * 4);
      float4 g0 = *(const float4*)(gnn + (size_t)n * 64 + g * 8);
      float4 g1 = *(const float4*)(gnn + (size_t)n * 64 + g * 8 + 4);
      float v0 = (g0.x + b2f((short)(own.x & 0xFFFF)) + a[0]) * (1.f / 3.f);
      float v1 = (g0.y + b2f((short)(own.x >> 16)) + a[1]) * (1.f / 3.f);
      float v2 = (g0.z + b2f((short)(own.y & 0xFFFF)) + a[2]) * (1.f / 3.f);
      float v3 = (g0.w + b2f((short)(own.y >> 16)) + a[3]) * (1.f / 3.f);
      float v4 = (g1.x + b2f((short)(own.z & 0xFFFF)) + a[4]) * (1.f / 3.f);
      float v5 = (g1.y + b2f((short)(own.z >> 16)) + a[5]) * (1.f / 3.f);
      float v6 = (g1.z + b2f((short)(own.w & 0xFFFF)) + a[6]) * (1.f / 3.f);
      float v7 = (g1.w + b2f((short)(own.w >> 16)) + a[7]) * (1.f / 3.f);
      uint4 o4;
      o4.x = packb(v0, v1);
      o4.y = packb(v2, v3);
      o4.z = packb(v4, v5);
      o4.w = packb(v6, v7);
      *(uint4*)(avgh + (size_t)n * 32 + g * 4) = o4;
    }
  }
}

// fp32 scatter fallback helpers
__global__ void prep_only(const float* __restrict__ pw, const float* __restrict__ wq,
                          const float* __restrict__ wk, const float* __restrict__ wv,
                          const float* __restrict__ wo, const float* __restrict__ w1,
                          const float* __restrict__ w2,
                          short* __restrict__ pwB, short* __restrict__ wqB,
                          short* __restrict__ wkB, short* __restrict__ wvB,
                          short* __restrict__ woB, short* __restrict__ w1B,
                          short* __restrict__ w2B) {
  prep_body(blockIdx.x * blockDim.x + threadIdx.x,
            pw, wq, wk, wv, wo, w1, w2, pwB, wqB, wkB, wvB, woB, w1B, w2B);
}
__global__ void zero_ws(int* __restrict__ p, int n) {
  int tid = blockIdx.x * blockDim.x + threadIdx.x;
  int NT = gridDim.x * blockDim.x;
  for (int i = tid; i < n; i += NT) p[i] = 0;
}
__global__ void gnn_scatter(const float* __restrict__ xin,
                            const int* __restrict__ src,
                            const int* __restrict__ dst,
                            const float* __restrict__ ew,
                            float* __restrict__ xout, int E) {
  int gid = blockIdx.x * blockDim.x + threadIdx.x;
  int e = gid >> 6;
  int d = gid & 63;
  if (e >= E) return;
  atomicAdd(&xout[(size_t)dst[e] * SD + d], xin[(size_t)src[e] * SD + d] * ew[e]);
}
__global__ void avg_from_f32(const float* __restrict__ gnn, const float* __restrict__ g1,
                             const float* __restrict__ g2, unsigned* __restrict__ avgh,
                             int n32) {
  int i = blockIdx.x * blockDim.x + threadIdx.x;
  if (i >= n32) return;
  float2 a = ((const float2*)gnn)[i];
  float2 b = ((const float2*)g1)[i];
  float2 c = ((const float2*)g2)[i];
  avgh[i] = packb((a.x + b.x + c.x) * (1.f / 3.f), (a.y + b.y + c.y) * (1.f / 3.f));
}

// ---------------------------------------------------------------------------
// MFMA transformer, 4-blocks/CU + setprio version. khs = K then P buffer.
// LDS 4x9216+256 = 37,120B.
// ---------------------------------------------------------------------------
__global__ __launch_bounds__(256, 4)
void seq_transformer(const int* __restrict__ seq, const int* __restrict__ lengths,
                     const float* __restrict__ bert, const short* __restrict__ avgh,
                     const float* __restrict__ pbias, const float* __restrict__ pos,
                     const short* __restrict__ pwB, const short* __restrict__ wqB,
                     const short* __restrict__ wkB, const short* __restrict__ wvB,
                     const short* __restrict__ woB, const short* __restrict__ w1B,
                     const short* __restrict__ w2B,
                     const float* __restrict__ b1, const float* __restrict__ b2,
                     const float* __restrict__ ln1g, const float* __restrict__ ln1b,
                     const float* __restrict__ ln2g, const float* __restrict__ ln2b,
                     const float* __restrict__ lnfg, const float* __restrict__ lnfb,
                     float* __restrict__ out) {
  __shared__ short xh[64 * PH];    // x (residual stream)
  __shared__ short qh[64 * PH];    // Q -> ctx -> ffn-h (own rows only)
  __shared__ short khs[64 * PH];   // K (cross-wave), then P (own rows)
  __shared__ short vt[64 * PH];    // V^T (cross-wave)
  __shared__ int   sidx[64];

  const int t = threadIdx.x;
  const int lane = t & 63;
  const int mt = t >> 6;
  const int quad = lane >> 4;
  const int c0 = lane & 15;
  const int b = blockIdx.x;
  const int arow = mt * 16 + c0;

  if (t < 64) sidx[t] = (t < SS) ? seq[b * SS + t] : 0;
  __syncthreads();

  const int len = lengths[b];
  const float alpha = (len <= 10) ? 0.3f : ((len >= 50) ? 0.7f : 0.5f);
  const float isq = 0.17677669529663687f;

  float kbias[4];
#pragma unroll
  for (int nt = 0; nt < 4; ++nt) {
    int key = nt * 16 + c0;
    kbias[nt] = (key < SS && sidx[key] != 0) ? 0.f : -1e9f;
  }

#pragma unroll
  for (int ir = 0; ir < 16; ++ir) {
    int s = mt * 16 + ir;
    short v = 0;
    if (s < SS) v = avgh[(size_t)sidx[s] * SD + lane];
    qh[s * PH + lane] = v;
  }

  {
    f32x4 o4[4];
    mm64(qh, pwB, arow, quad, lane, o4);
#pragma unroll
    for (int nt = 0; nt < 4; ++nt) {
      int c = nt * 16 + c0;
      float pbv = pbias[c];
#pragma unroll
      for (int r = 0; r < 4; ++r) {
        int row = mt * 16 + quad * 4 + r;
        short ov8 = 0;
        if (row < SS) {
          float g = o4[nt][r] + pbv;
          float xv = alpha * bert[(size_t)sidx[row] * SD + c] +
                     (1.f - alpha) * g + pos[row * SD + c];
          ov8 = f2b(xv);
        }
        xh[row * PH + c] = ov8;
      }
    }
  }

#pragma unroll 1
  for (int blk = 0; blk < NBLK; ++blk) {
    const short* Wq = wqB + blk * 4096;
    const short* Wk = wkB + blk * 4096;
    const short* Wv = wvB + blk * 4096;
    const short* Wo = woB + blk * 4096;
    const short* W1 = w1B + blk * 16384;
    const short* W2 = w2B + blk * 16384;

    __syncthreads();   // layer-top: khs/vt safe to rewrite (prev readers done)

    // ---- Q -> qh, K -> khs (own rows), V -> vt (own seq-cols, transposed)
    {
      f32x4 o4[4];
      mm64(xh, Wq, arow, quad, lane, o4);
#pragma unroll
      for (int nt = 0; nt < 4; ++nt) {
        int c = nt * 16 + c0;
#pragma unroll
        for (int r = 0; r < 4; ++r) qh[(mt * 16 + quad * 4 + r) * PH + c] = f2b(o4[nt][r]);
      }
      mm64(xh, Wk, arow, quad, lane, o4);
#pragma unroll
      for (int nt = 0; nt < 4; ++nt) {
        int c = nt * 16 + c0;
#pragma unroll
        for (int r = 0; r < 4; ++r) khs[(mt * 16 + quad * 4 + r) * PH + c] = f2b(o4[nt][r]);
      }
      mm64(xh, Wv, arow, quad, lane, o4);
#pragma unroll
      for (int nt = 0; nt < 4; ++nt) {
        int dim = nt * 16 + c0;
        unsigned p0 = packb(o4[nt][0], o4[nt][1]);
        unsigned p1 = packb(o4[nt][2], o4[nt][3]);
        *(uint2*)(vt + (size_t)dim * PH + mt * 16 + quad * 4) = make_uint2(p0, p1);
      }
    }
    __syncthreads();   // khs (K) / vt visible to all waves

    // ---- scores for BOTH heads (all khs reads complete before re-purpose)
    float p2[2][4][4];   // [h][nt][r]
    __builtin_amdgcn_s_setprio(1);
#pragma unroll
    for (int h = 0; h < 2; ++h) {
      bf16x8 aq = *(const bf16x8*)(qh + arow * PH + h * 32 + quad * 8);
#pragma unroll
      for (int nt = 0; nt < 4; ++nt) {
        int key = nt * 16 + c0;
        bf16x8 bk = *(const bf16x8*)(khs + key * PH + h * 32 + quad * 8);
        f32x4 acc = {0.f, 0.f, 0.f, 0.f};
        acc = __builtin_amdgcn_mfma_f32_16x16x32_bf16(aq, bk, acc, 0, 0, 0);
#pragma unroll
        for (int r = 0; r < 4; ++r) p2[h][nt][r] = fmaf(acc[r], isq, kbias[nt]);
      }
    }
    __builtin_amdgcn_s_setprio(0);
    __syncthreads();   // all waves done reading khs as K -> becomes P buffer

    // ---- per-head: softmax (regs) -> P -> khs own rows -> ctx
#pragma unroll
    for (int h = 0; h < 2; ++h) {
      {
        float mx[4], sm[4];
#pragma unroll
        for (int r = 0; r < 4; ++r)
          mx[r] = fmaxf(fmaxf(p2[h][0][r], p2[h][1][r]),
                        fmaxf(p2[h][2][r], p2[h][3][r]));
#pragma unroll
        for (int o = 1; o < 16; o <<= 1)
#pragma unroll
          for (int r = 0; r < 4; ++r) mx[r] = fmaxf(mx[r], __shfl_xor(mx[r], o, 64));
#pragma unroll
        for (int r = 0; r < 4; ++r) sm[r] = 0.f;
#pragma unroll
        for (int nt = 0; nt < 4; ++nt)
#pragma unroll
          for (int r = 0; r < 4; ++r) {
            float e = __expf(p2[h][nt][r] - mx[r]);
            p2[h][nt][r] = e;
            sm[r] += e;
          }
#pragma unroll
        for (int o = 1; o < 16; o <<= 1)
#pragma unroll
          for (int r = 0; r < 4; ++r) sm[r] += __shfl_xor(sm[r], o, 64);
#pragma unroll
        for (int r = 0; r < 4; ++r) {
          float inv = __builtin_amdgcn_rcpf(sm[r]);
          int q = mt * 16 + quad * 4 + r;
#pragma unroll
          for (int nt = 0; nt < 4; ++nt)
            khs[q * PH + nt * 16 + c0] = f2b(p2[h][nt][r] * inv);
        }
      }
      // ctx_h = P V_h -> overwrite qh own rows, cols h*32..h*32+31
      {
        bf16x8 a0 = *(const bf16x8*)(khs + arow * PH + quad * 8);
        bf16x8 a1 = *(const bf16x8*)(khs + arow * PH + 32 + quad * 8);
        __builtin_amdgcn_s_setprio(1);
#pragma unroll
        for (int nt = 0; nt < 2; ++nt) {
          int dim = h * 32 + nt * 16 + c0;
          bf16x8 b0 = *(const bf16x8*)(vt + (size_t)dim * PH + quad * 8);
          bf16x8 b1v = *(const bf16x8*)(vt + (size_t)dim * PH + 32 + quad * 8);
          f32x4 acc = {0.f, 0.f, 0.f, 0.f};
          acc = __builtin_amdgcn_mfma_f32_16x16x32_bf16(a0, b0, acc, 0, 0, 0);
          acc = __builtin_amdgcn_mfma_f32_16x16x32_bf16(a1, b1v, acc, 0, 0, 0);
#pragma unroll
          for (int r = 0; r < 4; ++r)
            qh[(mt * 16 + quad * 4 + r) * PH + dim] = f2b(acc[r]);
        }
        __builtin_amdgcn_s_setprio(0);
      }
    }

    // ---- O-projection + residual + LN1 -> xh (own rows)
    {
      f32x4 o4[4];
      mm64(qh, Wo, arow, quad, lane, o4);
      ln_epilogue(o4, xh, ln1g + blk * SD, ln1b + blk * SD, nullptr, mt, quad, c0);
    }

    // ---- FFN, own rows, no barriers (intra-wave LDS ordering)
    f32x4 facc[4];
#pragma unroll
    for (int nt = 0; nt < 4; ++nt) facc[nt] = (f32x4){0.f, 0.f, 0.f, 0.f};
#pragma unroll 1
    for (int c = 0; c < 4; ++c) {
      {
        bf16x8 a0 = *(const bf16x8*)(xh + arow * PH + quad * 8);
        bf16x8 a1 = *(const bf16x8*)(xh + arow * PH + 32 + quad * 8);
        __builtin_amdgcn_s_setprio(1);
        f32x4 accv[4];
#pragma unroll
        for (int nt = 0; nt < 4; ++nt) {
          int ntg = c * 4 + nt;
          f32x4 acc = {0.f, 0.f, 0.f, 0.f};
          acc = __builtin_amdgcn_mfma_f32_16x16x32_bf16(a0, ldB(W1, 0 * 16 + ntg, lane), acc, 0, 0, 0);
          acc = __builtin_amdgcn_mfma_f32_16x16x32_bf16(a1, ldB(W1, 1 * 16 + ntg, lane), acc, 0, 0, 0);
          accv[nt] = acc;
        }
        __builtin_amdgcn_s_setprio(0);
#pragma unroll
        for (int nt = 0; nt < 4; ++nt) {
          int cc = nt * 16 + c0;
          float b1v = b1[blk * 256 + c * 64 + cc];
#pragma unroll
          for (int r = 0; r < 4; ++r)
            qh[(mt * 16 + quad * 4 + r) * PH + cc] = f2b(gelu_fast(accv[nt][r] + b1v));
        }
      }
      {
        bf16x8 a0 = *(const bf16x8*)(qh + arow * PH + quad * 8);
        bf16x8 a1 = *(const bf16x8*)(qh + arow * PH + 32 + quad * 8);
        __builtin_amdgcn_s_setprio(1);
#pragma unroll
        for (int nt = 0; nt < 4; ++nt) {
          facc[nt] = __builtin_amdgcn_mfma_f32_16x16x32_bf16(a0, ldB(W2, (2 * c) * 4 + nt, lane), facc[nt], 0, 0, 0);
          facc[nt] = __builtin_amdgcn_mfma_f32_16x16x32_bf16(a1, ldB(W2, (2 * c + 1) * 4 + nt, lane), facc[nt], 0, 0, 0);
        }
        __builtin_amdgcn_s_setprio(0);
      }
    }

    // ---- residual + b2 + LN2 -> xh (own rows)
    ln_epilogue(facc, xh, ln2g + blk * SD, ln2b + blk * SD, b2 + blk * SD, mt, quad, c0);
  }
  __syncthreads();

  if (mt == 0) {
    int sl = len - 1;
    float val = b2f(xh[sl * PH + lane]);
    float2 ss = wred_sum2(val, val * val);
    float m = ss.x * (1.f / 64);
    float var = fmaxf(ss.y * (1.f / 64) - m * m, 0.f);
    float rs = rsqrtf(var + 1e-5f);
    out[b * SD + lane] = (val - m) * rs * lnfg[lane] + lnfb[lane];
  }
}

// ---------------------------------------------------------------------------
extern "C" void kernel_launch(void* const* d_in, const int* in_sizes, int n_in,
                              void* d_out, int out_size, void* d_ws, size_t ws_size,
                              hipStream_t stream) {
  const int*   seq   = (const int*)d_in[0];
  const int*   lens  = (const int*)d_in[1];
  const int*   ei    = (const int*)d_in[2];
  const float* ew    = (const float*)d_in[3];
  const float* bert  = (const float*)d_in[4];
  const float* gnn   = (const float*)d_in[5];
  const float* pw    = (const float*)d_in[6];
  const float* pb    = (const float*)d_in[7];
  const float* pos   = (const float*)d_in[8];
  const float* wq    = (const float*)d_in[9];
  const float* wk    = (const float*)d_in[10];
  const float* wv    = (const float*)d_in[11];
  const float* wo    = (const float*)d_in[12];
  const float* w1    = (const float*)d_in[13];
  const float* b1    = (const float*)d_in[14];
  const float* w2    = (const float*)d_in[15];
  const float* b2    = (const float*)d_in[16];
  const float* ln1g  = (const float*)d_in[17];
  const float* ln1b  = (const float*)d_in[18];
  const float* ln2g  = (const float*)d_in[19];
  const float* ln2b  = (const float*)d_in[20];
  const float* lnfg  = (const float*)d_in[21];
  const float* lnfb  = (const float*)d_in[22];
  float* out = (float*)d_out;

  const int E = in_sizes[2] / 2;          // 1,000,000
  const int B = in_sizes[0] / SS;         // 1024
  const int N = in_sizes[4] / SD;         // 100,001
  const int BS = B * SS;                  // 51,200

  const int* esrc = ei;
  const int* edst = ei + E;

  const int Nr = (N + 1023) & ~1023;
  const int NF = (N + 15) & ~15;
  const int n32 = N * 32;

  // ---- workspace layout; (cs, cap) degraded until it fits
  short* pwB; short* wqB; short* wkB; short* wvB; short* woB; short* w1B; short* w2B;
  unsigned* gnnh; unsigned* g1xh; unsigned* avgh;
  int* cntp; unsigned char* flags; int* ovcnt; int4* ov; int2* ep;
  int cs = 4, cap = 32;
  auto layout = [&](int cstride, int capv) -> size_t {
    pwB = (short*)d_ws;
    wqB = pwB + 4096;
    wkB = wqB + 8192;
    wvB = wkB + 8192;
    woB = wvB + 8192;
    w1B = woB + 8192;
    w2B = w1B + 32768;
    gnnh = (unsigned*)(w2B + 32768);
    g1xh = gnnh + (size_t)N * 32;
    cntp = (int*)(g1xh + (size_t)N * 32);
    flags = (unsigned char*)(cntp + (size_t)Nr * cstride);
    ovcnt = (int*)(flags + NF);
    ov = (int4*)(ovcnt + 4);
    ep = (int2*)(ov + OVCAP);
    avgh = gnnh;   // avgh ALIASES gnnh (dead after gather1)
    return (size_t)((char*)(ep + (size_t)N * capv) - (char*)d_ws);
  };
  size_t need = layout(4, 32); cs = 4; cap = 32;
  if (need > ws_size) { need = layout(1, 32); cs = 1; cap = 32; }
  if (need > ws_size) { need = layout(1, 24); cs = 1; cap = 24; }

  // fp32 fallback tables (overlay the ep region; ep unused in fallback)
  float* g1x = (float*)ep;
  float* g2x = g1x + (size_t)N * SD;
  size_t need_fb = (size_t)((char*)(g2x + (size_t)N * SD) - (char*)d_ws);

  if (need <= ws_size) {
    const int cntn = Nr * cs;
    zero_only<<<256, 256, 0, stream>>>(cntp, cntn, (int*)flags, NF / 4, ovcnt);
    gnn_build<<<2048, 256, 0, stream>>>(esrc, edst, ew, cntp, cs, cap, ep,
                                        ov, ovcnt, seq, flags, BS, E, N,
                                        gnn, gnnh, n32,
                                        pw, wq, wk, wv, wo, w1, w2,
                                        pwB, wqB, wkB, wvB, woB, w1B, w2B);
    gnn_gather1<<<2048, 256, 0, stream>>>(gnnh, cntp, cs, cap, ep, ov, ovcnt,
                                          g1xh, N);
    gnn_gather_avg<<<2048, 256, 0, stream>>>(g1xh, cntp, cs, cap, ep, ov, ovcnt,
                                             gnn, (unsigned*)avgh, N, flags);
  } else if (ws_size >= need_fb) {
    prep_only<<<50, 256, 0, stream>>>(pw, wq, wk, wv, wo, w1, w2,
                                      pwB, wqB, wkB, wvB, woB, w1B, w2B);
    zero_ws<<<1024, 256, 0, stream>>>((int*)g1x, 2 * N * SD);
    const long total = (long)E * 64;
    const int sblocks = (int)((total + 255) / 256);
    gnn_scatter<<<sblocks, 256, 0, stream>>>(gnn, esrc, edst, ew, g1x, E);
    gnn_scatter<<<sblocks, 256, 0, stream>>>(g1x, esrc, edst, ew, g2x, E);
    avg_from_f32<<<(n32 + 255) / 256, 256, 0, stream>>>(gnn, g1x, g2x,
                                                        (unsigned*)avgh, n32);
  }

  seq_transformer<<<B, 256, 0, stream>>>(
      seq, lens, bert, (const short*)avgh, pb, pos,
      pwB, wqB, wkB, wvB, woB, w1B, w2B,
      b1, b2, ln1g, ln1b, ln2g, ln2b, lnfg, lnfb, out);
}

// Round 15
// 290.940 us; speedup vs baseline: 1.0038x; 1.0038x over previous
//
#include <hip/hip_runtime.h>
#include <math.h>

// ---------------------------------------------------------------------------
// HybridBERT4RecGNN forward on MI355X (gfx950), round 26.
//
// R25 split verdict: setprio transformer WON (78.2 -> 68.6us, MfmaUtil
// 7.5 -> 8.9, VGPR 64 -> 52); build P=8 -> P=4 LOST the same ~10us (P=4
// partitions span 2 XCD L2s under round-robin -> reintroduces cross-XCD
// partial-line write amplification that R17 measured at ~8x).
// R26: revert build to P=8 (bid&7, R17-R24 proven form); keep setprio
// transformer and everything else byte-identical to R25.
// ---------------------------------------------------------------------------

typedef __attribute__((ext_vector_type(8))) short bf16x8;
typedef __attribute__((ext_vector_type(4))) float f32x4;

#define SD   64
#define SS   50
#define NBLK 2
#define PH   72    // LDS pitch in halves (144 B, 16B-aligned rows, 2-way banks max)
#define OVCAP 8192

__device__ __forceinline__ short f2b(float f) {  // fp32 -> bf16 RNE (HW cvt)
  union { __bf16 h; short s; } u;
  u.h = (__bf16)f;
  return u.s;
}
__device__ __forceinline__ float b2f(short s) {
  union { unsigned u; float f; } v;
  v.u = ((unsigned)(unsigned short)s) << 16;
  return v.f;
}
__device__ __forceinline__ unsigned packb(float a, float b) {
  union { __bf16 h; unsigned short s; } ua, ub;
  ua.h = (__bf16)a; ub.h = (__bf16)b;
  return (unsigned)ua.s | ((unsigned)ub.s << 16);
}
__device__ __forceinline__ float2 wred_sum2(float a, float b) {
#pragma unroll
  for (int o = 32; o > 0; o >>= 1) {
    a += __shfl_xor(a, o, 64);
    b += __shfl_xor(b, o, 64);
  }
  return make_float2(a, b);
}
// gelu(x) = 0.5x(1+tanh(u)) = x * sigmoid(2u);  sigmoid via v_rcp_f32.
__device__ __forceinline__ float gelu_fast(float x) {
  float u = 0.7978845608028654f * x * (1.0f + 0.044715f * x * x);
  float e = __expf(-2.f * u);
  return x * __builtin_amdgcn_rcpf(1.0f + e);
}

__device__ __forceinline__ bf16x8 ldB(const short* __restrict__ Wb, int tile, int lane) {
  return *(const bf16x8*)(Wb + ((size_t)tile * 64 + lane) * 8);
}

// [own 16 rows x K=64] @ [64x64] -> D own rows. A from LDS bf16 pitch PH.
// setprio(1) keeps the matrix pipe fed while co-resident blocks issue memory.
__device__ __forceinline__ void mm64(const short* A, const short* __restrict__ Wb,
                                     int arow, int quad, int lane, f32x4 o4[4]) {
  bf16x8 a0 = *(const bf16x8*)(A + arow * PH + quad * 8);
  bf16x8 a1 = *(const bf16x8*)(A + arow * PH + 32 + quad * 8);
  __builtin_amdgcn_s_setprio(1);
#pragma unroll
  for (int nt = 0; nt < 4; ++nt) {
    f32x4 acc = {0.f, 0.f, 0.f, 0.f};
    acc = __builtin_amdgcn_mfma_f32_16x16x32_bf16(a0, ldB(Wb, 0 * 4 + nt, lane), acc, 0, 0, 0);
    acc = __builtin_amdgcn_mfma_f32_16x16x32_bf16(a1, ldB(Wb, 1 * 4 + nt, lane), acc, 0, 0, 0);
    o4[nt] = acc;
  }
  __builtin_amdgcn_s_setprio(0);
}

// LN over 64 cols of D-layout values + residual from xh + optional bias.
__device__ __forceinline__ void ln_epilogue(f32x4 o4[4], short* xh,
                                            const float* __restrict__ g,
                                            const float* __restrict__ bta,
                                            const float* __restrict__ extrab,
                                            int mt, int quad, int c0) {
  float vals[4][4];
  float s1[4] = {0.f, 0.f, 0.f, 0.f}, s2[4] = {0.f, 0.f, 0.f, 0.f};
#pragma unroll
  for (int nt = 0; nt < 4; ++nt) {
    int c = nt * 16 + c0;
    float eb = extrab ? extrab[c] : 0.f;
#pragma unroll
    for (int r = 0; r < 4; ++r) {
      int row = mt * 16 + quad * 4 + r;
      float v = o4[nt][r] + b2f(xh[row * PH + c]) + eb;
      vals[nt][r] = v;
      s1[r] += v;
      s2[r] += v * v;
    }
  }
#pragma unroll
  for (int o = 1; o < 16; o <<= 1) {
#pragma unroll
    for (int r = 0; r < 4; ++r) {
      s1[r] += __shfl_xor(s1[r], o, 64);
      s2[r] += __shfl_xor(s2[r], o, 64);
    }
  }
  float mv[4], rv[4];
#pragma unroll
  for (int r = 0; r < 4; ++r) {
    float m = s1[r] * (1.f / 64);
    float var = fmaxf(s2[r] * (1.f / 64) - m * m, 0.f);
    mv[r] = m;
    rv[r] = rsqrtf(var + 1e-5f);
  }
#pragma unroll
  for (int nt = 0; nt < 4; ++nt) {
    int c = nt * 16 + c0;
    float gv = g[c], bv = bta[c];
#pragma unroll
    for (int r = 0; r < 4; ++r) {
      int row = mt * 16 + quad * 4 + r;
      xh[row * PH + c] = f2b((vals[nt][r] - mv[r]) * rv[r] * gv + bv);
    }
  }
}

// ---------------------------------------------------------------------------
// Weight prep body
// ---------------------------------------------------------------------------
__device__ __forceinline__ void prep_body(int tid,
    const float* __restrict__ pw, const float* __restrict__ wq,
    const float* __restrict__ wk, const float* __restrict__ wv,
    const float* __restrict__ wo, const float* __restrict__ w1,
    const float* __restrict__ w2,
    short* __restrict__ pwB, short* __restrict__ wqB,
    short* __restrict__ wkB, short* __restrict__ wvB,
    short* __restrict__ woB, short* __restrict__ w1B,
    short* __restrict__ w2B) {
  int lane = tid & 63;
  int tile = tid >> 6;
  const float* W; short* out; int K, N, base;
  if (tile < 8)        { W = pw; out = pwB; K = 64;  N = 64;  base = 0; }
  else if (tile < 24)  { W = wq; out = wqB; K = 64;  N = 64;  base = 8; }
  else if (tile < 40)  { W = wk; out = wkB; K = 64;  N = 64;  base = 24; }
  else if (tile < 56)  { W = wv; out = wvB; K = 64;  N = 64;  base = 40; }
  else if (tile < 72)  { W = wo; out = woB; K = 64;  N = 64;  base = 56; }
  else if (tile < 136) { W = w1; out = w1B; K = 64;  N = 256; base = 72; }
  else if (tile < 200) { W = w2; out = w2B; K = 256; N = 64;  base = 136; }
  else return;
  int lt = tile - base;
  int KT = K / 32, NT = N / 16;
  int nt = lt % NT; lt /= NT;
  int kt = lt % KT; lt /= KT;
  int m = lt;
  const float* Wm = W + (size_t)m * K * N;
  int kbase = kt * 32 + ((lane >> 4) * 8);
  int n = nt * 16 + (lane & 15);
  short v[8];
#pragma unroll
  for (int j = 0; j < 8; ++j) v[j] = f2b(Wm[(size_t)(kbase + j) * N + n]);
  *(bf16x8*)(out + ((size_t)(tile - base) * 64 + lane) * 8) = *(bf16x8*)v;
}

// Tiny kernel: zero counters/flags/ovcnt (kernel-based; memset banned).
__global__ void zero_only(int* __restrict__ cntp, int cntn,
                          int* __restrict__ flagsw, int nfw,
                          int* __restrict__ ovcnt) {
  int tid = blockIdx.x * blockDim.x + threadIdx.x;
  int NT = gridDim.x * blockDim.x;
  for (int i = tid; i < cntn; i += NT) cntp[i] = 0;
  for (int i = tid; i < nfw; i += NT) flagsw[i] = 0;
  if (tid < 4) ovcnt[tid] = 0;
}

// ---------------------------------------------------------------------------
// Fused: weight prep + fp32->bf16 cvt + flags + slot-direct CSR build.
// P=8 dst partitions (bid&7 -> XCD round-robin): each slot-table line is
// dirtied by exactly ONE XCD's L2 (R17-measured: kills the ~8x partial-line
// cross-XCD write amplification).
// ---------------------------------------------------------------------------
__global__ void gnn_build(const int* __restrict__ src, const int* __restrict__ dst,
                          const float* __restrict__ ew, int* __restrict__ cntp,
                          int cs, int cap, int2* __restrict__ ep,
                          int4* __restrict__ ov, int* __restrict__ ovcnt,
                          const int* __restrict__ seq,
                          unsigned char* __restrict__ flags, int BS,
                          int E, int Nn,
                          const float* __restrict__ gnn, unsigned* __restrict__ gnnh,
                          int n32,
                          const float* __restrict__ pw, const float* __restrict__ wq,
                          const float* __restrict__ wk, const float* __restrict__ wv,
                          const float* __restrict__ wo, const float* __restrict__ w1,
                          const float* __restrict__ w2,
                          short* __restrict__ pwB, short* __restrict__ wqB,
                          short* __restrict__ wkB, short* __restrict__ wvB,
                          short* __restrict__ woB, short* __restrict__ w1B,
                          short* __restrict__ w2B) {
  int tid = blockIdx.x * 256 + threadIdx.x;
  int NT = gridDim.x * 256;
  prep_body(tid, pw, wq, wk, wv, wo, w1, w2, pwB, wqB, wkB, wvB, woB, w1B, w2B);
  for (int i = tid; i < n32; i += NT) {
    float2 f = ((const float2*)gnn)[i];
    gnnh[i] = packb(f.x, f.y);
  }
  for (int i = tid; i < BS; i += NT) flags[seq[i]] = 1;
  int p = blockIdx.x & 7;
  int sub = blockIdx.x >> 3;
  int nsub = gridDim.x >> 3;
  int lo = (int)(((long)p * Nn) >> 3);
  int hi = (int)(((long)(p + 1) * Nn) >> 3);
  for (int e = sub * 256 + threadIdx.x; e < E; e += nsub * 256) {
    int d = dst[e];
    if (d >= lo && d < hi) {
      int pos = atomicAdd(&cntp[d * cs], 1);
      if (pos < cap) {
        ep[(size_t)d * cap + pos] = make_int2(src[e], __float_as_int(ew[e]));
      } else {
        int oi = atomicAdd(ovcnt, 1);
        if (oi < OVCAP) ov[oi] = make_int4(d, src[e], __float_as_int(ew[e]), 0);
      }
    }
  }
}

// ---------------------------------------------------------------------------
// Gather: half-wave (32 lanes) per node, 4 slots x 8 dims. ep speculative
// (|| cnt); rows predicated by slot+4b<end. 2 dependent levels for deg<=16.
// ---------------------------------------------------------------------------
__device__ __forceinline__ void gather_accum(float a[8], uint4 p, float w) {
  a[0] += b2f((short)(p.x & 0xFFFF)) * w;
  a[1] += b2f((short)(p.x >> 16)) * w;
  a[2] += b2f((short)(p.y & 0xFFFF)) * w;
  a[3] += b2f((short)(p.y >> 16)) * w;
  a[4] += b2f((short)(p.z & 0xFFFF)) * w;
  a[5] += b2f((short)(p.z >> 16)) * w;
  a[6] += b2f((short)(p.w & 0xFFFF)) * w;
  a[7] += b2f((short)(p.w >> 16)) * w;
}
__device__ __forceinline__ void gather_accum_idx(float a[8],
    const unsigned* __restrict__ tab, int srcn, float w, int g) {
  uint4 p = *(const uint4*)(tab + (size_t)srcn * 32 + g * 4);
  gather_accum(a, p, w);
}

__device__ __forceinline__ void gather_core(float a[8], int n, int slot, int g,
    const unsigned* __restrict__ tab, const int* __restrict__ cntp, int cs, int cap,
    const int2* __restrict__ ep, const int4* __restrict__ ov,
    const int* __restrict__ ovcnt, int Nn) {
  int deg = cntp[n * cs];                       // level-1, concurrent with:
  int2 e[4];
#pragma unroll
  for (int b = 0; b < 4; ++b)                   // slots 0..15 < cap, in-bounds
    e[b] = ep[(size_t)n * cap + slot + 4 * b];
  int end = min(deg, cap);
  uint4 r[4] = {};
#pragma unroll
  for (int b = 0; b < 4; ++b) {                 // level-2: predicated rows
    if (slot + 4 * b < end) {
      int s = min(max(e[b].x, 0), Nn - 1);
      r[b] = *(const uint4*)(tab + (size_t)s * 32 + g * 4);
    }
  }
#pragma unroll
  for (int b = 0; b < 4; ++b)
    if (slot + 4 * b < end) gather_accum(a, r[b], __int_as_float(e[b].y));
  for (int i = slot + 16; i < end; i += 4) {    // tail: 16 < deg <= cap (2.7%)
    int2 ee = ep[(size_t)n * cap + i];
    gather_accum_idx(a, tab, min(max(ee.x, 0), Nn - 1), __int_as_float(ee.y), g);
  }
  if (deg > cap && slot == 0) {   // rare path: scan overflow list once
    int ovn = min(max(*ovcnt, 0), OVCAP);
    for (int i = 0; i < ovn; ++i) {
      int4 eo = ov[i];
      if (eo.x == n) gather_accum_idx(a, tab, min(max(eo.y, 0), Nn - 1),
                                      __int_as_float(eo.z), g);
    }
  }
}

__global__ void gnn_gather1(const unsigned* __restrict__ xinh,
                            const int* __restrict__ cntp, int cs, int cap,
                            const int2* __restrict__ ep, const int4* __restrict__ ov,
                            const int* __restrict__ ovcnt,
                            unsigned* __restrict__ xouth, int Nn) {
  int l32 = threadIdx.x & 31;
  int slot = l32 >> 3, g = l32 & 7;
  for (int n = blockIdx.x * 8 + (threadIdx.x >> 5); n < Nn; n += gridDim.x * 8) {
    float a[8] = {0.f, 0.f, 0.f, 0.f, 0.f, 0.f, 0.f, 0.f};
    gather_core(a, n, slot, g, xinh, cntp, cs, cap, ep, ov, ovcnt, Nn);
#pragma unroll
    for (int o = 8; o < 32; o <<= 1)
#pragma unroll
      for (int j = 0; j < 8; ++j) a[j] += __shfl_xor(a[j], o, 64);
    if (slot == 0) {
      uint4 o4;
      o4.x = packb(a[0], a[1]);
      o4.y = packb(a[2], a[3]);
      o4.z = packb(a[4], a[5]);
      o4.w = packb(a[6], a[7]);
      *(uint4*)(xouth + (size_t)n * 32 + g * 4) = o4;
    }
  }
}

__global__ void gnn_gather_avg(const unsigned* __restrict__ x1h,
                               const int* __restrict__ cntp, int cs, int cap,
                               const int2* __restrict__ ep, const int4* __restrict__ ov,
                               const int* __restrict__ ovcnt,
                               const float* __restrict__ gnn,
                               unsigned* __restrict__ avgh, int Nn,
                               const unsigned char* __restrict__ flags) {
  int l32 = threadIdx.x & 31;
  int slot = l32 >> 3, g = l32 & 7;
  for (int n = blockIdx.x * 8 + (threadIdx.x >> 5); n < Nn; n += gridDim.x * 8) {
    if (!flags[n]) continue;   // avgh[n] never read by transformer
    float a[8] = {0.f, 0.f, 0.f, 0.f, 0.f, 0.f, 0.f, 0.f};
    gather_core(a, n, slot, g, x1h, cntp, cs, cap, ep, ov, ovcnt, Nn);
#pragma unroll
    for (int o = 8; o < 32; o <<= 1)
#pragma unroll
      for (int j = 0; j < 8; ++j) a[j] += __shfl_xor(a[j], o, 64);
    if (slot == 0) {
      uint4 own = *(const uint4*)(x1h + (size_t)n * 32 + g * 4);
      float4 g0 = *(const float4*)(gnn + (size_t)n * 64 + g * 8);
      float4 g1 = *(const float4*)(gnn + (size_t)n * 64 + g * 8 + 4);
      float v0 = (g0.x + b2f((short)(own.x & 0xFFFF)) + a[0]) * (1.f / 3.f);
      float v1 = (g0.y + b2f((short)(own.x >> 16)) + a[1]) * (1.f / 3.f);
      float v2 = (g0.z + b2f((short)(own.y & 0xFFFF)) + a[2]) * (1.f / 3.f);
      float v3 = (g0.w + b2f((short)(own.y >> 16)) + a[3]) * (1.f / 3.f);
      float v4 = (g1.x + b2f((short)(own.z & 0xFFFF)) + a[4]) * (1.f / 3.f);
      float v5 = (g1.y + b2f((short)(own.z >> 16)) + a[5]) * (1.f / 3.f);
      float v6 = (g1.z + b2f((short)(own.w & 0xFFFF)) + a[6]) * (1.f / 3.f);
      float v7 = (g1.w + b2f((short)(own.w >> 16)) + a[7]) * (1.f / 3.f);
      uint4 o4;
      o4.x = packb(v0, v1);
      o4.y = packb(v2, v3);
      o4.z = packb(v4, v5);
      o4.w = packb(v6, v7);
      *(uint4*)(avgh + (size_t)n * 32 + g * 4) = o4;
    }
  }
}

// fp32 scatter fallback helpers
__global__ void prep_only(const float* __restrict__ pw, const float* __restrict__ wq,
                          const float* __restrict__ wk, const float* __restrict__ wv,
                          const float* __restrict__ wo, const float* __restrict__ w1,
                          const float* __restrict__ w2,
                          short* __restrict__ pwB, short* __restrict__ wqB,
                          short* __restrict__ wkB, short* __restrict__ wvB,
                          short* __restrict__ woB, short* __restrict__ w1B,
                          short* __restrict__ w2B) {
  prep_body(blockIdx.x * blockDim.x + threadIdx.x,
            pw, wq, wk, wv, wo, w1, w2, pwB, wqB, wkB, wvB, woB, w1B, w2B);
}
__global__ void zero_ws(int* __restrict__ p, int n) {
  int tid = blockIdx.x * blockDim.x + threadIdx.x;
  int NT = gridDim.x * blockDim.x;
  for (int i = tid; i < n; i += NT) p[i] = 0;
}
__global__ void gnn_scatter(const float* __restrict__ xin,
                            const int* __restrict__ src,
                            const int* __restrict__ dst,
                            const float* __restrict__ ew,
                            float* __restrict__ xout, int E) {
  int gid = blockIdx.x * blockDim.x + threadIdx.x;
  int e = gid >> 6;
  int d = gid & 63;
  if (e >= E) return;
  atomicAdd(&xout[(size_t)dst[e] * SD + d], xin[(size_t)src[e] * SD + d] * ew[e]);
}
__global__ void avg_from_f32(const float* __restrict__ gnn, const float* __restrict__ g1,
                             const float* __restrict__ g2, unsigned* __restrict__ avgh,
                             int n32) {
  int i = blockIdx.x * blockDim.x + threadIdx.x;
  if (i >= n32) return;
  float2 a = ((const float2*)gnn)[i];
  float2 b = ((const float2*)g1)[i];
  float2 c = ((const float2*)g2)[i];
  avgh[i] = packb((a.x + b.x + c.x) * (1.f / 3.f), (a.y + b.y + c.y) * (1.f / 3.f));
}

// ---------------------------------------------------------------------------
// MFMA transformer, 4-blocks/CU + setprio version (R25-proven, 68.6us).
// khs = K then P buffer. LDS 4x9216+256 = 37,120B.
// ---------------------------------------------------------------------------
__global__ __launch_bounds__(256, 4)
void seq_transformer(const int* __restrict__ seq, const int* __restrict__ lengths,
                     const float* __restrict__ bert, const short* __restrict__ avgh,
                     const float* __restrict__ pbias, const float* __restrict__ pos,
                     const short* __restrict__ pwB, const short* __restrict__ wqB,
                     const short* __restrict__ wkB, const short* __restrict__ wvB,
                     const short* __restrict__ woB, const short* __restrict__ w1B,
                     const short* __restrict__ w2B,
                     const float* __restrict__ b1, const float* __restrict__ b2,
                     const float* __restrict__ ln1g, const float* __restrict__ ln1b,
                     const float* __restrict__ ln2g, const float* __restrict__ ln2b,
                     const float* __restrict__ lnfg, const float* __restrict__ lnfb,
                     float* __restrict__ out) {
  __shared__ short xh[64 * PH];    // x (residual stream)
  __shared__ short qh[64 * PH];    // Q -> ctx -> ffn-h (own rows only)
  __shared__ short khs[64 * PH];   // K (cross-wave), then P (own rows)
  __shared__ short vt[64 * PH];    // V^T (cross-wave)
  __shared__ int   sidx[64];

  const int t = threadIdx.x;
  const int lane = t & 63;
  const int mt = t >> 6;
  const int quad = lane >> 4;
  const int c0 = lane & 15;
  const int b = blockIdx.x;
  const int arow = mt * 16 + c0;

  if (t < 64) sidx[t] = (t < SS) ? seq[b * SS + t] : 0;
  __syncthreads();

  const int len = lengths[b];
  const float alpha = (len <= 10) ? 0.3f : ((len >= 50) ? 0.7f : 0.5f);
  const float isq = 0.17677669529663687f;

  float kbias[4];
#pragma unroll
  for (int nt = 0; nt < 4; ++nt) {
    int key = nt * 16 + c0;
    kbias[nt] = (key < SS && sidx[key] != 0) ? 0.f : -1e9f;
  }

#pragma unroll
  for (int ir = 0; ir < 16; ++ir) {
    int s = mt * 16 + ir;
    short v = 0;
    if (s < SS) v = avgh[(size_t)sidx[s] * SD + lane];
    qh[s * PH + lane] = v;
  }

  {
    f32x4 o4[4];
    mm64(qh, pwB, arow, quad, lane, o4);
#pragma unroll
    for (int nt = 0; nt < 4; ++nt) {
      int c = nt * 16 + c0;
      float pbv = pbias[c];
#pragma unroll
      for (int r = 0; r < 4; ++r) {
        int row = mt * 16 + quad * 4 + r;
        short ov8 = 0;
        if (row < SS) {
          float g = o4[nt][r] + pbv;
          float xv = alpha * bert[(size_t)sidx[row] * SD + c] +
                     (1.f - alpha) * g + pos[row * SD + c];
          ov8 = f2b(xv);
        }
        xh[row * PH + c] = ov8;
      }
    }
  }

#pragma unroll 1
  for (int blk = 0; blk < NBLK; ++blk) {
    const short* Wq = wqB + blk * 4096;
    const short* Wk = wkB + blk * 4096;
    const short* Wv = wvB + blk * 4096;
    const short* Wo = woB + blk * 4096;
    const short* W1 = w1B + blk * 16384;
    const short* W2 = w2B + blk * 16384;

    __syncthreads();   // layer-top: khs/vt safe to rewrite (prev readers done)

    // ---- Q -> qh, K -> khs (own rows), V -> vt (own seq-cols, transposed)
    {
      f32x4 o4[4];
      mm64(xh, Wq, arow, quad, lane, o4);
#pragma unroll
      for (int nt = 0; nt < 4; ++nt) {
        int c = nt * 16 + c0;
#pragma unroll
        for (int r = 0; r < 4; ++r) qh[(mt * 16 + quad * 4 + r) * PH + c] = f2b(o4[nt][r]);
      }
      mm64(xh, Wk, arow, quad, lane, o4);
#pragma unroll
      for (int nt = 0; nt < 4; ++nt) {
        int c = nt * 16 + c0;
#pragma unroll
        for (int r = 0; r < 4; ++r) khs[(mt * 16 + quad * 4 + r) * PH + c] = f2b(o4[nt][r]);
      }
      mm64(xh, Wv, arow, quad, lane, o4);
#pragma unroll
      for (int nt = 0; nt < 4; ++nt) {
        int dim = nt * 16 + c0;
        unsigned p0 = packb(o4[nt][0], o4[nt][1]);
        unsigned p1 = packb(o4[nt][2], o4[nt][3]);
        *(uint2*)(vt + (size_t)dim * PH + mt * 16 + quad * 4) = make_uint2(p0, p1);
      }
    }
    __syncthreads();   // khs (K) / vt visible to all waves

    // ---- scores for BOTH heads (all khs reads complete before re-purpose)
    float p2[2][4][4];   // [h][nt][r]
    __builtin_amdgcn_s_setprio(1);
#pragma unroll
    for (int h = 0; h < 2; ++h) {
      bf16x8 aq = *(const bf16x8*)(qh + arow * PH + h * 32 + quad * 8);
#pragma unroll
      for (int nt = 0; nt < 4; ++nt) {
        int key = nt * 16 + c0;
        bf16x8 bk = *(const bf16x8*)(khs + key * PH + h * 32 + quad * 8);
        f32x4 acc = {0.f, 0.f, 0.f, 0.f};
        acc = __builtin_amdgcn_mfma_f32_16x16x32_bf16(aq, bk, acc, 0, 0, 0);
#pragma unroll
        for (int r = 0; r < 4; ++r) p2[h][nt][r] = fmaf(acc[r], isq, kbias[nt]);
      }
    }
    __builtin_amdgcn_s_setprio(0);
    __syncthreads();   // all waves done reading khs as K -> becomes P buffer

    // ---- per-head: softmax (regs) -> P -> khs own rows -> ctx
#pragma unroll
    for (int h = 0; h < 2; ++h) {
      {
        float mx[4], sm[4];
#pragma unroll
        for (int r = 0; r < 4; ++r)
          mx[r] = fmaxf(fmaxf(p2[h][0][r], p2[h][1][r]),
                        fmaxf(p2[h][2][r], p2[h][3][r]));
#pragma unroll
        for (int o = 1; o < 16; o <<= 1)
#pragma unroll
          for (int r = 0; r < 4; ++r) mx[r] = fmaxf(mx[r], __shfl_xor(mx[r], o, 64));
#pragma unroll
        for (int r = 0; r < 4; ++r) sm[r] = 0.f;
#pragma unroll
        for (int nt = 0; nt < 4; ++nt)
#pragma unroll
          for (int r = 0; r < 4; ++r) {
            float e = __expf(p2[h][nt][r] - mx[r]);
            p2[h][nt][r] = e;
            sm[r] += e;
          }
#pragma unroll
        for (int o = 1; o < 16; o <<= 1)
#pragma unroll
          for (int r = 0; r < 4; ++r) sm[r] += __shfl_xor(sm[r], o, 64);
#pragma unroll
        for (int r = 0; r < 4; ++r) {
          float inv = __builtin_amdgcn_rcpf(sm[r]);
          int q = mt * 16 + quad * 4 + r;
#pragma unroll
          for (int nt = 0; nt < 4; ++nt)
            khs[q * PH + nt * 16 + c0] = f2b(p2[h][nt][r] * inv);
        }
      }
      // ctx_h = P V_h -> overwrite qh own rows, cols h*32..h*32+31
      {
        bf16x8 a0 = *(const bf16x8*)(khs + arow * PH + quad * 8);
        bf16x8 a1 = *(const bf16x8*)(khs + arow * PH + 32 + quad * 8);
        __builtin_amdgcn_s_setprio(1);
#pragma unroll
        for (int nt = 0; nt < 2; ++nt) {
          int dim = h * 32 + nt * 16 + c0;
          bf16x8 b0 = *(const bf16x8*)(vt + (size_t)dim * PH + quad * 8);
          bf16x8 b1v = *(const bf16x8*)(vt + (size_t)dim * PH + 32 + quad * 8);
          f32x4 acc = {0.f, 0.f, 0.f, 0.f};
          acc = __builtin_amdgcn_mfma_f32_16x16x32_bf16(a0, b0, acc, 0, 0, 0);
          acc = __builtin_amdgcn_mfma_f32_16x16x32_bf16(a1, b1v, acc, 0, 0, 0);
#pragma unroll
          for (int r = 0; r < 4; ++r)
            qh[(mt * 16 + quad * 4 + r) * PH + dim] = f2b(acc[r]);
        }
        __builtin_amdgcn_s_setprio(0);
      }
    }

    // ---- O-projection + residual + LN1 -> xh (own rows)
    {
      f32x4 o4[4];
      mm64(qh, Wo, arow, quad, lane, o4);
      ln_epilogue(o4, xh, ln1g + blk * SD, ln1b + blk * SD, nullptr, mt, quad, c0);
    }

    // ---- FFN, own rows, no barriers (intra-wave LDS ordering)
    f32x4 facc[4];
#pragma unroll
    for (int nt = 0; nt < 4; ++nt) facc[nt] = (f32x4){0.f, 0.f, 0.f, 0.f};
#pragma unroll 1
    for (int c = 0; c < 4; ++c) {
      {
        bf16x8 a0 = *(const bf16x8*)(xh + arow * PH + quad * 8);
        bf16x8 a1 = *(const bf16x8*)(xh + arow * PH + 32 + quad * 8);
        __builtin_amdgcn_s_setprio(1);
        f32x4 accv[4];
#pragma unroll
        for (int nt = 0; nt < 4; ++nt) {
          int ntg = c * 4 + nt;
          f32x4 acc = {0.f, 0.f, 0.f, 0.f};
          acc = __builtin_amdgcn_mfma_f32_16x16x32_bf16(a0, ldB(W1, 0 * 16 + ntg, lane), acc, 0, 0, 0);
          acc = __builtin_amdgcn_mfma_f32_16x16x32_bf16(a1, ldB(W1, 1 * 16 + ntg, lane), acc, 0, 0, 0);
          accv[nt] = acc;
        }
        __builtin_amdgcn_s_setprio(0);
#pragma unroll
        for (int nt = 0; nt < 4; ++nt) {
          int cc = nt * 16 + c0;
          float b1v = b1[blk * 256 + c * 64 + cc];
#pragma unroll
          for (int r = 0; r < 4; ++r)
            qh[(mt * 16 + quad * 4 + r) * PH + cc] = f2b(gelu_fast(accv[nt][r] + b1v));
        }
      }
      {
        bf16x8 a0 = *(const bf16x8*)(qh + arow * PH + quad * 8);
        bf16x8 a1 = *(const bf16x8*)(qh + arow * PH + 32 + quad * 8);
        __builtin_amdgcn_s_setprio(1);
#pragma unroll
        for (int nt = 0; nt < 4; ++nt) {
          facc[nt] = __builtin_amdgcn_mfma_f32_16x16x32_bf16(a0, ldB(W2, (2 * c) * 4 + nt, lane), facc[nt], 0, 0, 0);
          facc[nt] = __builtin_amdgcn_mfma_f32_16x16x32_bf16(a1, ldB(W2, (2 * c + 1) * 4 + nt, lane), facc[nt], 0, 0, 0);
        }
        __builtin_amdgcn_s_setprio(0);
      }
    }

    // ---- residual + b2 + LN2 -> xh (own rows)
    ln_epilogue(facc, xh, ln2g + blk * SD, ln2b + blk * SD, b2 + blk * SD, mt, quad, c0);
  }
  __syncthreads();

  if (mt == 0) {
    int sl = len - 1;
    float val = b2f(xh[sl * PH + lane]);
    float2 ss = wred_sum2(val, val * val);
    float m = ss.x * (1.f / 64);
    float var = fmaxf(ss.y * (1.f / 64) - m * m, 0.f);
    float rs = rsqrtf(var + 1e-5f);
    out[b * SD + lane] = (val - m) * rs * lnfg[lane] + lnfb[lane];
  }
}

// ---------------------------------------------------------------------------
extern "C" void kernel_launch(void* const* d_in, const int* in_sizes, int n_in,
                              void* d_out, int out_size, void* d_ws, size_t ws_size,
                              hipStream_t stream) {
  const int*   seq   = (const int*)d_in[0];
  const int*   lens  = (const int*)d_in[1];
  const int*   ei    = (const int*)d_in[2];
  const float* ew    = (const float*)d_in[3];
  const float* bert  = (const float*)d_in[4];
  const float* gnn   = (const float*)d_in[5];
  const float* pw    = (const float*)d_in[6];
  const float* pb    = (const float*)d_in[7];
  const float* pos   = (const float*)d_in[8];
  const float* wq    = (const float*)d_in[9];
  const float* wk    = (const float*)d_in[10];
  const float* wv    = (const float*)d_in[11];
  const float* wo    = (const float*)d_in[12];
  const float* w1    = (const float*)d_in[13];
  const float* b1    = (const float*)d_in[14];
  const float* w2    = (const float*)d_in[15];
  const float* b2    = (const float*)d_in[16];
  const float* ln1g  = (const float*)d_in[17];
  const float* ln1b  = (const float*)d_in[18];
  const float* ln2g  = (const float*)d_in[19];
  const float* ln2b  = (const float*)d_in[20];
  const float* lnfg  = (const float*)d_in[21];
  const float* lnfb  = (const float*)d_in[22];
  float* out = (float*)d_out;

  const int E = in_sizes[2] / 2;          // 1,000,000
  const int B = in_sizes[0] / SS;         // 1024
  const int N = in_sizes[4] / SD;         // 100,001
  const int BS = B * SS;                  // 51,200

  const int* esrc = ei;
  const int* edst = ei + E;

  const int Nr = (N + 1023) & ~1023;
  const int NF = (N + 15) & ~15;
  const int n32 = N * 32;

  // ---- workspace layout; (cs, cap) degraded until it fits
  short* pwB; short* wqB; short* wkB; short* wvB; short* woB; short* w1B; short* w2B;
  unsigned* gnnh; unsigned* g1xh; unsigned* avgh;
  int* cntp; unsigned char* flags; int* ovcnt; int4* ov; int2* ep;
  int cs = 4, cap = 32;
  auto layout = [&](int cstride, int capv) -> size_t {
    pwB = (short*)d_ws;
    wqB = pwB + 4096;
    wkB = wqB + 8192;
    wvB = wkB + 8192;
    woB = wvB + 8192;
    w1B = woB + 8192;
    w2B = w1B + 32768;
    gnnh = (unsigned*)(w2B + 32768);
    g1xh = gnnh + (size_t)N * 32;
    cntp = (int*)(g1xh + (size_t)N * 32);
    flags = (unsigned char*)(cntp + (size_t)Nr * cstride);
    ovcnt = (int*)(flags + NF);
    ov = (int4*)(ovcnt + 4);
    ep = (int2*)(ov + OVCAP);
    avgh = gnnh;   // avgh ALIASES gnnh (dead after gather1)
    return (size_t)((char*)(ep + (size_t)N * capv) - (char*)d_ws);
  };
  size_t need = layout(4, 32); cs = 4; cap = 32;
  if (need > ws_size) { need = layout(1, 32); cs = 1; cap = 32; }
  if (need > ws_size) { need = layout(1, 24); cs = 1; cap = 24; }

  // fp32 fallback tables (overlay the ep region; ep unused in fallback)
  float* g1x = (float*)ep;
  float* g2x = g1x + (size_t)N * SD;
  size_t need_fb = (size_t)((char*)(g2x + (size_t)N * SD) - (char*)d_ws);

  if (need <= ws_size) {
    const int cntn = Nr * cs;
    zero_only<<<256, 256, 0, stream>>>(cntp, cntn, (int*)flags, NF / 4, ovcnt);
    gnn_build<<<2048, 256, 0, stream>>>(esrc, edst, ew, cntp, cs, cap, ep,
                                        ov, ovcnt, seq, flags, BS, E, N,
                                        gnn, gnnh, n32,
                                        pw, wq, wk, wv, wo, w1, w2,
                                        pwB, wqB, wkB, wvB, woB, w1B, w2B);
    gnn_gather1<<<2048, 256, 0, stream>>>(gnnh, cntp, cs, cap, ep, ov, ovcnt,
                                          g1xh, N);
    gnn_gather_avg<<<2048, 256, 0, stream>>>(g1xh, cntp, cs, cap, ep, ov, ovcnt,
                                             gnn, (unsigned*)avgh, N, flags);
  } else if (ws_size >= need_fb) {
    prep_only<<<50, 256, 0, stream>>>(pw, wq, wk, wv, wo, w1, w2,
                                      pwB, wqB, wkB, wvB, woB, w1B, w2B);
    zero_ws<<<1024, 256, 0, stream>>>((int*)g1x, 2 * N * SD);
    const long total = (long)E * 64;
    const int sblocks = (int)((total + 255) / 256);
    gnn_scatter<<<sblocks, 256, 0, stream>>>(gnn, esrc, edst, ew, g1x, E);
    gnn_scatter<<<sblocks, 256, 0, stream>>>(g1x, esrc, edst, ew, g2x, E);
    avg_from_f32<<<(n32 + 255) / 256, 256, 0, stream>>>(gnn, g1x, g2x,
                                                        (unsigned*)avgh, n32);
  }

  seq_transformer<<<B, 256, 0, stream>>>(
      seq, lens, bert, (const short*)avgh, pb, pos,
      pwB, wqB, wkB, wvB, woB, w1B, w2B,
      b1, b2, ln1g, ln1b, ln2g, ln2b, lnfg, lnfb, out);
}